// Round 10
// baseline (432.422 us; speedup 1.0000x reference)
//
#include <hip/hip_runtime.h>
#include <cstdint>
#include <cstddef>

// Problem constants (fixed by the reference)
#define TOKENS 8192
#define INF    4096
#define OUTF   4096

typedef int v4i __attribute__((ext_vector_type(4)));

// ---------------------------------------------------------------------------
// Kernel 1: pack int32 -> int8 into workspace (x8 then w8, row-major).
// Thread t handles 4 consecutive int4-chunks -> one 16B packed store.
// ---------------------------------------------------------------------------
__global__ __launch_bounds__(256) void pack_i8_kernel(
    const int* __restrict__ xi, const int* __restrict__ wi,
    uint8_t* __restrict__ x8, uint8_t* __restrict__ w8) {
  const int NXT = (TOKENS * INF) / 16;   // 2097152 x-tasks (16 ints each)
  const int NT  = 2048 * 256;            // 524288 threads
  int tid = blockIdx.x * 256 + threadIdx.x;
#pragma unroll 1
  for (int g = 0; g < 6; ++g) {          // 6 * 524288 = 3145728 tasks total
    int t = g * NT + tid;
    const int4* s;
    int4* d;
    if (t < NXT) {
      s = (const int4*)xi + 4 * (size_t)t;
      d = (int4*)x8 + t;
    } else {
      int t2 = t - NXT;
      s = (const int4*)wi + 4 * (size_t)t2;
      d = (int4*)w8 + t2;
    }
    int4 v0 = s[0], v1 = s[1], v2 = s[2], v3 = s[3];
    int4 p;
    p.x = (v0.x & 255) | ((v0.y & 255) << 8) | ((v0.z & 255) << 16) | (v0.w << 24);
    p.y = (v1.x & 255) | ((v1.y & 255) << 8) | ((v1.z & 255) << 16) | (v1.w << 24);
    p.z = (v2.x & 255) | ((v2.y & 255) << 8) | ((v2.z & 255) << 16) | (v2.w << 24);
    p.w = (v3.x & 255) | ((v3.y & 255) << 8) | ((v3.z & 255) << 16) | (v3.w << 24);
    *d = p;
  }
}

// ---------------------------------------------------------------------------
// Branchless exact-GeLU via Abramowitz-Stegun 7.1.26 erf (|err| <= 1.5e-7).
// ---------------------------------------------------------------------------
__device__ __forceinline__ float gelu_exact(float y) {
  float x = y * 0.70710678118654752f;   // y / sqrt(2)
  float s = fabsf(x);
  float t = __builtin_amdgcn_rcpf(fmaf(s, 0.3275911f, 1.0f));
  float p = t * fmaf(t, fmaf(t, fmaf(t, fmaf(t, 1.061405429f, -1.453152027f),
                                     1.421413741f), -0.284496736f),
                     0.254829592f);
  float e = __expf(-s * s);
  float er = fmaf(-p, e, 1.0f);         // erf(|x|)
  er = copysignf(er, x);
  return 0.5f * y * (1.0f + er);
}

__device__ __forceinline__ void barrier_fenced() {
  asm volatile("" ::: "memory");
  __builtin_amdgcn_s_barrier();
  asm volatile("" ::: "memory");
}

// ---------------------------------------------------------------------------
// Kernel 2: int8 GEMM, BM=BN=256, BK=128 bytes (2 ksteps of K=64),
// 256 threads / 4 waves (2x2), wave tile 128x128, mfma_i32_16x16x64_i8.
//
// R9 post-mortem: with 8 waves x 128x64 tiles, per-CU LDS-read time
// (~192 b128/iter) ~= MFMA time -> serial sum caps util at ~47% (measured
// 43%). This round HALVES LDS read traffic per MFMA: 4 waves x 128x128
// wave tile (128 b128/iter), acc 8x8 frags (256 VGPR, 1 wave/SIMD).
// k1 fragment reads interleaved under k0's MFMA groups (in-wave ILP; no
// barrier partner needed at 1 wave/SIMD), pinned via sched_group_barrier.
// Sync rotation unchanged (proven race-free R8/R9):
//   [top: vmcnt(0); barrier (publish tile kt); gll burst tile kt+1; body]
// 8-way XOR chunk swizzle via inverse-permuted global source + linear gll
// dest (rule 21; 0 conflicts measured R4/R7/R8/R9). Output: int32.
// ---------------------------------------------------------------------------
__global__ __launch_bounds__(256, 1) void gemm_i8_gelu_q_kernel(
    const uint8_t* __restrict__ x8, const uint8_t* __restrict__ w8,
    const float* __restrict__ bias, const float* __restrict__ pa,
    const float* __restrict__ pb, int* __restrict__ out) {
  __shared__ char sm[131072];

  const int tid = threadIdx.x;
  const int l   = tid & 63;
  const int wv  = tid >> 6;            // 0..3
  const int wr  = wv >> 1;             // 0..1  (M wave row)
  const int wc  = wv & 1;              // 0..1  (N wave col)
  const int lr  = l & 15;              // fragment row
  const int lg  = l >> 4;              // k-group 0..3 (16B chunk in K=64)

  // XCD-aware bijective swizzle (512 blocks % 8 == 0)
  int id = blockIdx.x;
  int wg = (id & 7) * 64 + (id >> 3);
  const int m0 = (wg >> 4) * 256;      // 32 row-bands
  const int n0 = (wg & 15) * 256;      // 16 col-bands

  const float av = pa[0];
  const float bv = pb[0];

  // ---- staging: wave wv + instr J covers rows wv*64 + J*8 + (l>>3);
  // linear LDS dest; source chunk inverse-swizzled (LDS[r][c]=G[r][c^(r&7)]).
  const int grow = (wv << 6) + (l >> 3);
  const int gch  = ((l & 7) ^ ((l >> 3) & 7)) << 4;
  const uint8_t* gA = x8 + (size_t)(m0 + grow) * INF + gch;
  const uint8_t* gB = w8 + (size_t)(n0 + grow) * INF + gch;
  const int dwv = wv * 8192;           // + J*1024 (+32768 for B, +bo for buf)

  // ---- fragment read offsets (row&7 == l&7 for all frag rows) ----
  int aoff[8], boff[8], sb0, sb1;
#pragma unroll
  for (int m = 0; m < 8; ++m) aoff[m] = (wr * 128 + m * 16 + lr) * 128;
#pragma unroll
  for (int n = 0; n < 8; ++n) boff[n] = 32768 + (wc * 128 + n * 16 + lr) * 128;
  sb0 = ((0 + lg) ^ (l & 7)) << 4;
  sb1 = ((4 + lg) ^ (l & 7)) << 4;

  v4i acc[8][8];                       // 256 VGPR accumulator
#pragma unroll
  for (int m = 0; m < 8; ++m)
#pragma unroll
    for (int n = 0; n < 8; ++n) acc[m][n] = (v4i){0, 0, 0, 0};

#define GLL(gsrc, ldst)                                                       \
  __builtin_amdgcn_global_load_lds(                                           \
      (const __attribute__((address_space(1))) unsigned*)(gsrc),              \
      (__attribute__((address_space(3))) unsigned*)(ldst), 16, 0, 0);

#define GLA(T, J) GLL(gA + (size_t)(J) * 8 * INF + (size_t)(T) * 128,         \
                      sm + (((T) & 1) << 16) + dwv + (J) * 1024)
#define GLB(T, J) GLL(gB + (size_t)(J) * 8 * INF + (size_t)(T) * 128,         \
                      sm + (((T) & 1) << 16) + 32768 + dwv + (J) * 1024)

#define LD(off) (*(const v4i*)(sbr + (off)))
#define MM(ACC, AF, BF)                                                       \
  ACC = __builtin_amdgcn_mfma_i32_16x16x64_i8(AF, BF, ACC, 0, 0, 0)
#define SGB(m, n) __builtin_amdgcn_sched_group_barrier((m), (n), 0)

  // One K128-iter. DS: stage tile kt+1 (compile-time 0/1).
#define ITER(DS)                                                              \
  {                                                                           \
    const char* sbr = sm + ((kt & 1) << 16);                                  \
    const int T = kt + 1;                                                     \
    asm volatile("s_waitcnt vmcnt(0)" ::: "memory"); /* tile kt landed */     \
    barrier_fenced();                 /* publish; prev iter reads done */     \
    if (DS) {                                                                 \
      GLA(T, 0); GLA(T, 1); GLA(T, 2); GLA(T, 3);                             \
      GLA(T, 4); GLA(T, 5); GLA(T, 6); GLA(T, 7);                             \
      GLB(T, 0); GLB(T, 1); GLB(T, 2); GLB(T, 3);                             \
      GLB(T, 4); GLB(T, 5); GLB(T, 6); GLB(T, 7);                             \
    }                                                                         \
    v4i a[8], b[8], c[8], d[8];                                               \
    _Pragma("unroll")                                                         \
    for (int i = 0; i < 8; ++i) a[i] = LD(aoff[i] + sb0);                     \
    _Pragma("unroll")                                                         \
    for (int i = 0; i < 8; ++i) b[i] = LD(boff[i] + sb0);                     \
    /* k0 groups 0-3 (pure MFMA) */                                           \
    _Pragma("unroll")                                                         \
    for (int m = 0; m < 4; ++m)                                               \
      _Pragma("unroll")                                                       \
      for (int n = 0; n < 8; ++n) MM(acc[m][n], a[m], b[n]);                  \
    /* k0 groups 4-7, k1 reads folded between groups */                       \
    _Pragma("unroll")                                                         \
    for (int m = 4; m < 8; ++m) {                                             \
      _Pragma("unroll")                                                       \
      for (int n = 0; n < 8; ++n) MM(acc[m][n], a[m], b[n]);                  \
      c[2 * (m - 4) + 0] = LD(aoff[2 * (m - 4) + 0] + sb1);                   \
      c[2 * (m - 4) + 1] = LD(aoff[2 * (m - 4) + 1] + sb1);                   \
      d[2 * (m - 4) + 0] = LD(boff[2 * (m - 4) + 0] + sb1);                   \
      d[2 * (m - 4) + 1] = LD(boff[2 * (m - 4) + 1] + sb1);                   \
    }                                                                         \
    /* k1 */                                                                  \
    _Pragma("unroll")                                                         \
    for (int m = 0; m < 8; ++m)                                               \
      _Pragma("unroll")                                                       \
      for (int n = 0; n < 8; ++n) MM(acc[m][n], c[m], d[n]);                  \
    /* pin: k0 reads, 32 MFMA, then (8 MFMA + 4 reads)x4, then 64 MFMA */     \
    SGB(0x100, 16);                                                           \
    SGB(0x008, 32);                                                           \
    SGB(0x008, 8); SGB(0x100, 4);                                             \
    SGB(0x008, 8); SGB(0x100, 4);                                             \
    SGB(0x008, 8); SGB(0x100, 4);                                             \
    SGB(0x008, 8); SGB(0x100, 4);                                             \
    SGB(0x008, 64);                                                           \
  }

  // prologue: stage tile 0 (iter 0's vmcnt(0)+barrier publishes it)
  GLA(0, 0); GLA(0, 1); GLA(0, 2); GLA(0, 3);
  GLA(0, 4); GLA(0, 5); GLA(0, 6); GLA(0, 7);
  GLB(0, 0); GLB(0, 1); GLB(0, 2); GLB(0, 3);
  GLB(0, 4); GLB(0, 5); GLB(0, 6); GLB(0, 7);

#pragma unroll 1
  for (int kt = 0; kt < 31; ++kt) ITER(1)
  {
    const int kt = 31;
    ITER(0)
  }

  // ---- epilogue: dequant + bias + exact GeLU + requant, write INT32 ----
  float bvals[8];
#pragma unroll
  for (int n = 0; n < 8; ++n) bvals[n] = bias[n0 + wc * 128 + n * 16 + lr];

#pragma unroll
  for (int m = 0; m < 8; ++m) {
    int rowb = m0 + wr * 128 + m * 16 + lg * 4;
#pragma unroll
    for (int q = 0; q < 4; ++q) {
      size_t rb = (size_t)(rowb + q) * OUTF;
#pragma unroll
      for (int n = 0; n < 8; ++n) {
        float f = fmaf(av, (float)acc[m][n][q], bvals[n]);
        float g = gelu_exact(f);
        float r = __builtin_rintf(g * bv);
        r = fminf(fmaxf(r, -128.0f), 127.0f);
        out[rb + (size_t)(n0 + wc * 128 + n * 16 + lr)] = (int)r;
      }
    }
  }
#undef GLL
#undef GLA
#undef GLB
#undef LD
#undef MM
#undef SGB
#undef ITER
}

// ---------------------------------------------------------------------------
extern "C" void kernel_launch(void* const* d_in, const int* in_sizes, int n_in,
                              void* d_out, int out_size, void* d_ws,
                              size_t ws_size, hipStream_t stream) {
  const int*   xi   = (const int*)d_in[0];
  const int*   wi   = (const int*)d_in[1];
  const float* bias = (const float*)d_in[2];
  const float* pa   = (const float*)d_in[3];
  const float* pb   = (const float*)d_in[4];
  int*         out  = (int*)d_out;

  uint8_t* x8 = (uint8_t*)d_ws;                         // 33554432 B
  uint8_t* w8 = x8 + (size_t)TOKENS * INF;              // 16777216 B
  // requires ws_size >= 50331648

  pack_i8_kernel<<<2048, 256, 0, stream>>>(xi, wi, x8, w8);

  dim3 grid((TOKENS / 256) * (OUTF / 256));             // 512 blocks
  gemm_i8_gelu_q_kernel<<<grid, 256, 0, stream>>>(x8, w8, bias, pa, pb, out);
}